// Round 6
// baseline (723.143 us; speedup 1.0000x reference)
//
#include <hip/hip_runtime.h>
#include <hip/hip_bf16.h>

typedef __bf16 bf16x8 __attribute__((ext_vector_type(8)));
typedef float f32x4 __attribute__((ext_vector_type(4)));
typedef unsigned short u16x4 __attribute__((ext_vector_type(4)));
typedef unsigned short u16x8 __attribute__((ext_vector_type(8)));

#define DEVI __device__ __forceinline__

constexpr int N_TOK = 2048;   // B*T
constexpr int DIM   = 2048;   // D
constexpr int NEXP  = 64;     // E
constexpr int FDIM  = 512;    // F
constexpr int TOPK  = 4;      // K
constexpr int NSH   = 2;      // S
constexpr int HSH   = 2048;   // HS

constexpr int BK = 64, KS = 8;

#define WAIT_VM0 asm volatile("s_waitcnt vmcnt(0)" ::: "memory")
#define WAIT_VM8 asm volatile("s_waitcnt vmcnt(8)" ::: "memory")
#define WAIT_LG0 asm volatile("s_waitcnt lgkmcnt(0)" ::: "memory")
#define SBAR __builtin_amdgcn_s_barrier()
#define SCHED0 __builtin_amdgcn_sched_barrier(0)

DEVI unsigned short f2b(float f) {
  union { float fv; unsigned u; } v; v.fv = f;
  unsigned r = v.u + 0x7fffu + ((v.u >> 16) & 1u);
  return (unsigned short)(r >> 16);
}
DEVI float b2f(unsigned short h) {
  union { unsigned u; float f; } v; v.u = ((unsigned)h) << 16;
  return v.f;
}
DEVI void gll16(const void* g, void* l) {
  __builtin_amdgcn_global_load_lds((const __attribute__((address_space(1))) unsigned*)g,
                                   (__attribute__((address_space(3))) unsigned*)l, 16, 0, 0);
}

// ---------------- x -> bf16 ----------------
__global__ void cvt_x_kernel(const float* __restrict__ x, unsigned short* __restrict__ xb) {
  const size_t i = ((size_t)blockIdx.x * 256 + threadIdx.x) * 8;
  const float4 a = *reinterpret_cast<const float4*>(x + i);
  const float4 b = *reinterpret_cast<const float4*>(x + i + 4);
  u16x8 o;
  o[0] = f2b(a.x); o[1] = f2b(a.y); o[2] = f2b(a.z); o[3] = f2b(a.w);
  o[4] = f2b(b.x); o[5] = f2b(b.y); o[6] = f2b(b.z); o[7] = f2b(b.w);
  *reinterpret_cast<u16x8*>(xb + i) = o;
}

// ---------------- shared weights: transpose + bf16 ----------------
__global__ __launch_bounds__(256)
void tr_shared_kernel(const float* __restrict__ swu, const float* __restrict__ swg,
                      const float* __restrict__ swd, unsigned short* __restrict__ swuT,
                      unsigned short* __restrict__ swgT, unsigned short* __restrict__ swdT) {
  __shared__ float Lf[64][68];
  const int tid = threadIdx.x;
  const int r0 = blockIdx.x * 64, c0 = blockIdx.y * 64;
  const int z = blockIdx.z, mat = z >> 1;
  const size_t soff = (size_t)(z & 1) * DIM * HSH;
  const float* in = (mat == 0 ? swu : mat == 1 ? swg : swd) + soff;
  unsigned short* ot = (mat == 0 ? swuT : mat == 1 ? swgT : swdT) + soff;
  #pragma unroll
  for (int j = 0; j < 4; ++j) {
    const int idx = j * 1024 + tid * 4;
    const int row = idx >> 6, col = idx & 63;
    const float4 v = *reinterpret_cast<const float4*>(in + (size_t)(r0 + row) * 2048 + c0 + col);
    *reinterpret_cast<float4*>(&Lf[row][col]) = v;
  }
  __syncthreads();
  #pragma unroll
  for (int j = 0; j < 4; ++j) {
    const int idx = j * 1024 + tid * 4;
    const int orow = idx >> 6, ocol = idx & 63;
    u16x4 o;
    o[0] = f2b(Lf[ocol][orow]);     o[1] = f2b(Lf[ocol + 1][orow]);
    o[2] = f2b(Lf[ocol + 2][orow]); o[3] = f2b(Lf[ocol + 3][orow]);
    *reinterpret_cast<u16x4*>(ot + (size_t)(c0 + orow) * 2048 + r0 + ocol) = o;
  }
}

// ---------------- Router (also emits token -> (expert, slot)) ----------------
__global__ __launch_bounds__(256)
void router_kernel(const float* __restrict__ x, const float* __restrict__ rw,
                   const float* __restrict__ rb, int* __restrict__ cnt,
                   int* __restrict__ listTok, float* __restrict__ listW,
                   int* __restrict__ tokEP) {
  __shared__ float Lx[8][128];
  const int tid = threadIdx.x;
  const int lane = tid & 63;
  const int wave = tid >> 6;
  const int tokBase = blockIdx.x * 8;

  float acc0 = 0.f, acc1 = 0.f;
  for (int dc = 0; dc < DIM; dc += 128) {
    __syncthreads();
    {
      const int idx = tid * 4;
      const int row = idx >> 7, col = idx & 127;
      *reinterpret_cast<float4*>(&Lx[row][col]) =
          *reinterpret_cast<const float4*>(x + (size_t)(tokBase + row) * DIM + dc + col);
    }
    __syncthreads();
    #pragma unroll 16
    for (int dd = 0; dd < 128; ++dd) {
      const float r = rw[(size_t)(dc + dd) * NEXP + lane];
      acc0 = fmaf(Lx[wave * 2 + 0][dd], r, acc0);
      acc1 = fmaf(Lx[wave * 2 + 1][dd], r, acc1);
    }
  }

  const float bias = rb[lane];
  #pragma unroll
  for (int t = 0; t < 2; ++t) {
    const float v = (t == 0) ? acc0 : acc1;
    const int token = tokBase + wave * 2 + t;
    float m = v;
    #pragma unroll
    for (int o = 32; o > 0; o >>= 1) m = fmaxf(m, __shfl_xor(m, o));
    const float p = expf(v - m);
    float ss = p;
    #pragma unroll
    for (int o = 32; o > 0; o >>= 1) ss += __shfl_xor(ss, o);
    const float score = p / ss;
    float cur = v + bias;
    float wk[TOPK]; int ik[TOPK]; float wsum = 0.f;
    #pragma unroll
    for (int k = 0; k < TOPK; ++k) {
      float tm = cur;
      #pragma unroll
      for (int o = 32; o > 0; o >>= 1) tm = fmaxf(tm, __shfl_xor(tm, o));
      const unsigned long long msk = __ballot(cur == tm);
      const int sel = (int)__builtin_ctzll(msk);
      const float w = __shfl(score, sel);
      wk[k] = w; ik[k] = sel; wsum += w;
      if (lane == sel) cur = -3.4e38f;
    }
    if (lane < TOPK) {
      const int e = ik[lane];
      const float w = wk[lane] / wsum;
      const int slot = atomicAdd(&cnt[e], 1);
      listTok[(size_t)e * N_TOK + slot] = token;
      listW[(size_t)e * N_TOK + slot] = w;
      tokEP[token * TOPK + lane] = (e << 16) | slot;
    }
  }
}

__global__ void scan_kernel(const int* __restrict__ cnt, int* __restrict__ off) {
  if (threadIdx.x == 0) {
    int s = 0;
    for (int e = 0; e < NEXP; ++e) { off[e] = s; s += cnt[e]; }
  }
}

// ---------------- Routed up (fused U+G): BM=128, BN=64, 2-phase dbuf ----------------
__global__ __launch_bounds__(256, 2)
void up_routed(const unsigned short* __restrict__ xb,
               const float* __restrict__ Wu, const float* __restrict__ Wg,
               const int* __restrict__ cnt, const int* __restrict__ off,
               const int* __restrict__ listTok, const float* __restrict__ listW,
               unsigned short* __restrict__ H) {
  constexpr int NT = DIM / BK;  // 32
  const int tid = threadIdx.x;
  const int f0 = blockIdx.x * 64;
  const int e  = blockIdx.y;
  const int m0 = blockIdx.z * 128;
  const int c = cnt[e];
  if (m0 >= c) return;
  const int rcnt = min(128, c - m0);
  const int rowbase = off[e] + m0;

  __shared__ __align__(16) unsigned short Al[2][KS][128][8];
  __shared__ __align__(16) unsigned short BuL[2][KS][64][8];
  __shared__ __align__(16) unsigned short BgL[2][KS][64][8];
  __shared__ float wSs[128];

  if (tid < 128) wSs[tid] = (tid < rcnt) ? listW[(size_t)e * N_TOK + m0 + tid] : 0.f;
  __syncthreads();

  const int wid = tid >> 6, l = tid & 63;
  const int wm = wid >> 1, wn = wid & 1;
  const int lc = l & 15, hi = l >> 4;

  const int t0 = listTok[(size_t)e * N_TOK + m0 + min(l, rcnt - 1)];
  const int t1 = listTok[(size_t)e * N_TOK + m0 + min(64 + l, rcnt - 1)];
  const unsigned short* pa0 = xb + (size_t)t0 * DIM;
  const unsigned short* pa1 = xb + (size_t)t1 * DIM;
  const float* wub = Wu + (size_t)e * DIM * FDIM + f0;
  const float* wgb = Wg + (size_t)e * DIM * FDIM + f0;

  const int q = tid & 31, p = tid >> 5;
  const int c4 = (q & 15) * 4, kh = q >> 4;

  f32x4 rBu[4], rBg[4];
  auto loadB = [&](int g) {
    const int d0 = g * BK;
    #pragma unroll
    for (int j = 0; j < 4; ++j)
      rBu[j] = *reinterpret_cast<const f32x4*>(wub + (size_t)(d0 + p * 8 + kh * 4 + j) * FDIM + c4);
    #pragma unroll
    for (int j = 0; j < 4; ++j)
      rBg[j] = *reinterpret_cast<const f32x4*>(wgb + (size_t)(d0 + p * 8 + kh * 4 + j) * FDIM + c4);
  };
  auto stageA = [&](int g, int b) {
    const int d0 = g * BK;
    gll16(pa0 + d0 + (2 * wid) * 8,     &Al[b][2 * wid][0][0]);
    gll16(pa1 + d0 + (2 * wid) * 8,     &Al[b][2 * wid][64][0]);
    gll16(pa0 + d0 + (2 * wid + 1) * 8, &Al[b][2 * wid + 1][0][0]);
    gll16(pa1 + d0 + (2 * wid + 1) * 8, &Al[b][2 * wid + 1][64][0]);
  };
  auto writeB = [&](int b) {
    #pragma unroll
    for (int cc = 0; cc < 4; ++cc) {
      u16x4 vu, vg;
      #pragma unroll
      for (int j = 0; j < 4; ++j) { vu[j] = f2b(rBu[j][cc]); vg[j] = f2b(rBg[j][cc]); }
      *reinterpret_cast<u16x4*>(&BuL[b][p][c4 + cc][kh * 4]) = vu;
      *reinterpret_cast<u16x4*>(&BgL[b][p][c4 + cc][kh * 4]) = vg;
    }
  };

  f32x4 aU[4][2], aG[4][2];
  #pragma unroll
  for (int i = 0; i < 4; ++i)
    #pragma unroll
    for (int j = 0; j < 2; ++j) { aU[i][j] = f32x4{0,0,0,0}; aG[i][j] = f32x4{0,0,0,0}; }

  // prologue
  loadB(0);
  stageA(0, 0);
  SCHED0;
  writeB(0);
  loadB(1);
  WAIT_VM8; WAIT_LG0; SBAR;

  for (int g = 0; g < NT; ++g) {
    const int b = g & 1;
    if (g + 1 < NT) {
      stageA(g + 1, b ^ 1);
      SCHED0;
      writeB(b ^ 1);
      if (g + 2 < NT) loadB(g + 2);
    }
    #pragma unroll
    for (int ks = 0; ks < 2; ++ks) {
      bf16x8 af[4], bu[2], bg[2];
      #pragma unroll
      for (int i = 0; i < 4; ++i)
        af[i] = *reinterpret_cast<const bf16x8*>(&Al[b][ks * 4 + hi][wm * 64 + i * 16 + lc][0]);
      #pragma unroll
      for (int i = 0; i < 2; ++i) {
        bu[i] = *reinterpret_cast<const bf16x8*>(&BuL[b][ks * 4 + hi][wn * 32 + i * 16 + lc][0]);
        bg[i] = *reinterpret_cast<const bf16x8*>(&BgL[b][ks * 4 + hi][wn * 32 + i * 16 + lc][0]);
      }
      #pragma unroll
      for (int mi = 0; mi < 4; ++mi)
        #pragma unroll
        for (int ni = 0; ni < 2; ++ni) {
          aU[mi][ni] = __builtin_amdgcn_mfma_f32_16x16x32_bf16(af[mi], bu[ni], aU[mi][ni], 0, 0, 0);
          aG[mi][ni] = __builtin_amdgcn_mfma_f32_16x16x32_bf16(af[mi], bg[ni], aG[mi][ni], 0, 0, 0);
        }
    }
    if (g + 1 < NT) {
      if (g + 2 < NT) { WAIT_VM8; } else { WAIT_VM0; }
      WAIT_LG0; SBAR;
    }
  }

  #pragma unroll
  for (int mi = 0; mi < 4; ++mi)
    #pragma unroll
    for (int ni = 0; ni < 2; ++ni)
      #pragma unroll
      for (int r2 = 0; r2 < 4; ++r2) {
        const int row = wm * 64 + mi * 16 + hi * 4 + r2;
        if (row < rcnt) {
          const int col = f0 + wn * 32 + ni * 16 + lc;
          const float g = aG[mi][ni][r2], u = aU[mi][ni][r2];
          const float h = (g / (1.f + __expf(-g))) * u * wSs[row];
          H[(size_t)(rowbase + row) * FDIM + col] = f2b(h);
        }
      }
}

// ---------------- Shared up (fused U+G): BM=128, BN=64, 2-phase dbuf ----------------
__global__ __launch_bounds__(256, 2)
void up_shared(const unsigned short* __restrict__ xb,
               const unsigned short* __restrict__ WuT, const unsigned short* __restrict__ WgT,
               unsigned short* __restrict__ H) {
  constexpr int NT = DIM / BK;  // 32
  const int tid = threadIdx.x;
  const int f0 = blockIdx.x * 64;
  const int s  = blockIdx.y;
  const int m0 = blockIdx.z * 128;

  __shared__ __align__(16) unsigned short Al[2][KS][128][8];
  __shared__ __align__(16) unsigned short Bu[2][KS][64][8];
  __shared__ __align__(16) unsigned short Bg[2][KS][64][8];

  const int wid = tid >> 6, l = tid & 63;
  const int wm = wid >> 1, wn = wid & 1;
  const int lc = l & 15, hi = l >> 4;

  const unsigned short* pa0 = xb + (size_t)(m0 + l) * DIM;
  const unsigned short* pa1 = xb + (size_t)(m0 + 64 + l) * DIM;
  const unsigned short* pbu = WuT + (size_t)s * HSH * DIM + (size_t)(f0 + l) * DIM;
  const unsigned short* pbg = WgT + (size_t)s * HSH * DIM + (size_t)(f0 + l) * DIM;

  auto stage = [&](int g, int b) {
    const int d0 = g * BK;
    gll16(pa0 + d0 + (2 * wid) * 8,     &Al[b][2 * wid][0][0]);
    gll16(pa1 + d0 + (2 * wid) * 8,     &Al[b][2 * wid][64][0]);
    gll16(pa0 + d0 + (2 * wid + 1) * 8, &Al[b][2 * wid + 1][0][0]);
    gll16(pa1 + d0 + (2 * wid + 1) * 8, &Al[b][2 * wid + 1][64][0]);
    gll16(pbu + d0 + (2 * wid) * 8,     &Bu[b][2 * wid][0][0]);
    gll16(pbu + d0 + (2 * wid + 1) * 8, &Bu[b][2 * wid + 1][0][0]);
    gll16(pbg + d0 + (2 * wid) * 8,     &Bg[b][2 * wid][0][0]);
    gll16(pbg + d0 + (2 * wid + 1) * 8, &Bg[b][2 * wid + 1][0][0]);
  };

  f32x4 aU[4][2], aG[4][2];
  #pragma unroll
  for (int i = 0; i < 4; ++i)
    #pragma unroll
    for (int j = 0; j < 2; ++j) { aU[i][j] = f32x4{0,0,0,0}; aG[i][j] = f32x4{0,0,0,0}; }

  stage(0, 0);
  WAIT_VM0; SBAR;

  for (int g = 0; g < NT; ++g) {
    const int b = g & 1;
    if (g + 1 < NT) stage(g + 1, b ^ 1);
    #pragma unroll
    for (int ks = 0; ks < 2; ++ks) {
      bf16x8 af[4], bu[2], bg[2];
      #pragma unroll
      for (int i = 0; i < 4; ++i)
        af[i] = *reinterpret_cast<const bf16x8*>(&Al[b][ks * 4 + hi][wm * 64 + i * 16 + lc][0]);
      #pragma unroll
      for (int i = 0; i < 2; ++i) {
        bu[i] = *reinterpret_cast<const bf16x8*>(&Bu[b][ks * 4 + hi][wn * 32 + i * 16 + lc][0]);
        bg[i] = *reinterpret_cast<const bf16x8*>(&Bg[b][ks * 4 + hi][wn * 32 + i * 16 + lc][0]);
      }
      #pragma unroll
      for (int mi = 0; mi < 4; ++mi)
        #pragma unroll
        for (int ni = 0; ni < 2; ++ni) {
          aU[mi][ni] = __builtin_amdgcn_mfma_f32_16x16x32_bf16(af[mi], bu[ni], aU[mi][ni], 0, 0, 0);
          aG[mi][ni] = __builtin_amdgcn_mfma_f32_16x16x32_bf16(af[mi], bg[ni], aG[mi][ni], 0, 0, 0);
        }
    }
    if (g + 1 < NT) { WAIT_VM0; SBAR; }
  }

  #pragma unroll
  for (int mi = 0; mi < 4; ++mi)
    #pragma unroll
    for (int ni = 0; ni < 2; ++ni)
      #pragma unroll
      for (int r2 = 0; r2 < 4; ++r2) {
        const int row = wm * 64 + mi * 16 + hi * 4 + r2;
        const int col = f0 + wn * 32 + ni * 16 + lc;
        const float g = aG[mi][ni][r2], u = aU[mi][ni][r2];
        H[((size_t)s * N_TOK + m0 + row) * HSH + col] = f2b((g / (1.f + __expf(-g))) * u);
      }
}

// ---------------- Shared down: out = Hs @ swdT (both segs), BM=64, BN=128 ----------------
__global__ __launch_bounds__(256, 3)
void down_shared(const unsigned short* __restrict__ Hs, const unsigned short* __restrict__ swdT,
                 float* __restrict__ out) {
  constexpr int NT = 2 * HSH / BK;  // 64
  const int tid = threadIdx.x;
  const int x0 = blockIdx.x * 128;
  const int m0 = blockIdx.z * 64;

  __shared__ __align__(16) unsigned short Al[2][KS][64][8];
  __shared__ __align__(16) unsigned short Bl[2][KS][128][8];

  const int wid = tid >> 6, l = tid & 63;
  const int wm = wid >> 1, wn = wid & 1;
  const int lc = l & 15, hi = l >> 4;

  auto stage = [&](int g, int b) {
    const int seg = g >> 5;
    const int d0 = (g & 31) * BK;
    const unsigned short* sA = Hs + ((size_t)seg * N_TOK + m0 + l) * HSH + d0;
    const unsigned short* b0 = swdT + (size_t)seg * HSH * DIM + (size_t)(x0 + l) * HSH + d0;
    const unsigned short* b1 = b0 + (size_t)64 * HSH;
    gll16(sA + (2 * wid) * 8,     &Al[b][2 * wid][0][0]);
    gll16(sA + (2 * wid + 1) * 8, &Al[b][2 * wid + 1][0][0]);
    gll16(b0 + (2 * wid) * 8,     &Bl[b][2 * wid][0][0]);
    gll16(b1 + (2 * wid) * 8,     &Bl[b][2 * wid][64][0]);
    gll16(b0 + (2 * wid + 1) * 8, &Bl[b][2 * wid + 1][0][0]);
    gll16(b1 + (2 * wid + 1) * 8, &Bl[b][2 * wid + 1][64][0]);
  };

  f32x4 acc[2][4];
  #pragma unroll
  for (int i = 0; i < 2; ++i)
    #pragma unroll
    for (int j = 0; j < 4; ++j) acc[i][j] = f32x4{0,0,0,0};

  stage(0, 0);
  WAIT_VM0; SBAR;

  for (int g = 0; g < NT; ++g) {
    const int b = g & 1;
    if (g + 1 < NT) stage(g + 1, b ^ 1);
    #pragma unroll
    for (int ks = 0; ks < 2; ++ks) {
      bf16x8 af[2], bq[4];
      #pragma unroll
      for (int i = 0; i < 2; ++i)
        af[i] = *reinterpret_cast<const bf16x8*>(&Al[b][ks * 4 + hi][wm * 32 + i * 16 + lc][0]);
      #pragma unroll
      for (int i = 0; i < 4; ++i)
        bq[i] = *reinterpret_cast<const bf16x8*>(&Bl[b][ks * 4 + hi][wn * 64 + i * 16 + lc][0]);
      #pragma unroll
      for (int mi = 0; mi < 2; ++mi)
        #pragma unroll
        for (int ni = 0; ni < 4; ++ni)
          acc[mi][ni] = __builtin_amdgcn_mfma_f32_16x16x32_bf16(af[mi], bq[ni], acc[mi][ni], 0, 0, 0);
    }
    if (g + 1 < NT) { WAIT_VM0; SBAR; }
  }

  #pragma unroll
  for (int mi = 0; mi < 2; ++mi)
    #pragma unroll
    for (int ni = 0; ni < 4; ++ni)
      #pragma unroll
      for (int r2 = 0; r2 < 4; ++r2) {
        const int row = wm * 32 + mi * 16 + hi * 4 + r2;
        const int col = x0 + wn * 64 + ni * 16 + lc;
        out[(size_t)(m0 + row) * DIM + col] = acc[mi][ni][r2];
      }
}

// ---------------- Routed down: P[slot] = Hr @ wd (no atomics), 2-phase dbuf ----------------
__global__ __launch_bounds__(256, 2)
void down_routed(const unsigned short* __restrict__ Hr, const float* __restrict__ wd,
                 const int* __restrict__ cnt, const int* __restrict__ off,
                 unsigned short* __restrict__ P) {
  constexpr int NT = FDIM / BK;  // 8
  const int tid = threadIdx.x;
  const int x0 = blockIdx.x * 128;
  const int e  = blockIdx.y;
  const int m0 = blockIdx.z * 128;
  const int c = cnt[e];
  if (m0 >= c) return;
  const int rcnt = min(128, c - m0);
  const int rowbase = off[e] + m0;

  __shared__ __align__(16) unsigned short Al[2][KS][128][8];
  __shared__ __align__(16) unsigned short Bl[2][KS][128][8];

  const int wid = tid >> 6, l = tid & 63;
  const int wm = wid >> 1, wn = wid & 1;
  const int lc = l & 15, hi = l >> 4;

  const unsigned short* pa0 = Hr + (size_t)(rowbase + min(l, rcnt - 1)) * FDIM;
  const unsigned short* pa1 = Hr + (size_t)(rowbase + min(64 + l, rcnt - 1)) * FDIM;
  const float* bw = wd + (size_t)e * FDIM * DIM + x0;

  const int f4 = tid & 31, p = tid >> 5;
  const int c4 = f4 * 4;

  f32x4 rB[2][4];
  auto loadB = [&](int g) {
    const int d0 = g * BK;
    #pragma unroll
    for (int s2 = 0; s2 < 2; ++s2)
      #pragma unroll
      for (int j = 0; j < 4; ++j)
        rB[s2][j] = *reinterpret_cast<const f32x4*>(bw + (size_t)(d0 + p * 8 + s2 * 4 + j) * DIM + c4);
  };
  auto stageA = [&](int g, int b) {
    const int d0 = g * BK;
    gll16(pa0 + d0 + (2 * wid) * 8,     &Al[b][2 * wid][0][0]);
    gll16(pa1 + d0 + (2 * wid) * 8,     &Al[b][2 * wid][64][0]);
    gll16(pa0 + d0 + (2 * wid + 1) * 8, &Al[b][2 * wid + 1][0][0]);
    gll16(pa1 + d0 + (2 * wid + 1) * 8, &Al[b][2 * wid + 1][64][0]);
  };
  auto writeB = [&](int b) {
    #pragma unroll
    for (int cc = 0; cc < 4; ++cc) {
      u16x8 v;
      v[0] = f2b(rB[0][0][cc]); v[1] = f2b(rB[0][1][cc]);
      v[2] = f2b(rB[0][2][cc]); v[3] = f2b(rB[0][3][cc]);
      v[4] = f2b(rB[1][0][cc]); v[5] = f2b(rB[1][1][cc]);
      v[6] = f2b(rB[1][2][cc]); v[7] = f2b(rB[1][3][cc]);
      *reinterpret_cast<u16x8*>(&Bl[b][p][c4 + cc][0]) = v;
    }
  };

  f32x4 acc[4][4];
  #pragma unroll
  for (int i = 0; i < 4; ++i)
    #pragma unroll
    for (int j = 0; j < 4; ++j) acc[i][j] = f32x4{0,0,0,0};

  loadB(0);
  stageA(0, 0);
  SCHED0;
  writeB(0);
  loadB(1);
  WAIT_VM8; WAIT_LG0; SBAR;

  for (int g = 0; g < NT; ++g) {
    const int b = g & 1;
    if (g + 1 < NT) {
      stageA(g + 1, b ^ 1);
      SCHED0;
      writeB(b ^ 1);
      if (g + 2 < NT) loadB(g + 2);
    }
    #pragma unroll
    for (int ks = 0; ks < 2; ++ks) {
      bf16x8 af[4], bq[4];
      #pragma unroll
      for (int i = 0; i < 4; ++i)
        af[i] = *reinterpret_cast<const bf16x8*>(&Al[b][ks * 4 + hi][wm * 64 + i * 16 + lc][0]);
      #pragma unroll
      for (int i = 0; i < 4; ++i)
        bq[i] = *reinterpret_cast<const bf16x8*>(&Bl[b][ks * 4 + hi][wn * 64 + i * 16 + lc][0]);
      #pragma unroll
      for (int mi = 0; mi < 4; ++mi)
        #pragma unroll
        for (int ni = 0; ni < 4; ++ni)
          acc[mi][ni] = __builtin_amdgcn_mfma_f32_16x16x32_bf16(af[mi], bq[ni], acc[mi][ni], 0, 0, 0);
    }
    if (g + 1 < NT) {
      if (g + 2 < NT) { WAIT_VM8; } else { WAIT_VM0; }
      WAIT_LG0; SBAR;
    }
  }

  #pragma unroll
  for (int mi = 0; mi < 4; ++mi)
    #pragma unroll
    for (int ni = 0; ni < 4; ++ni)
      #pragma unroll
      for (int r2 = 0; r2 < 4; ++r2) {
        const int row = wm * 64 + mi * 16 + hi * 4 + r2;
        if (row < rcnt) {
          const int col = x0 + wn * 64 + ni * 16 + lc;
          P[(size_t)(rowbase + row) * DIM + col] = f2b(acc[mi][ni][r2]);
        }
      }
}

// ---------------- Combine: out[n] += sum_k P[slot(n,k)] ----------------
__global__ __launch_bounds__(256)
void combine_kernel(const int* __restrict__ tokEP, const int* __restrict__ off,
                    const unsigned short* __restrict__ P, float* __restrict__ out) {
  const int n = blockIdx.x;
  const int tid = threadIdx.x;
  int rows[4];
  #pragma unroll
  for (int k = 0; k < TOPK; ++k) {
    const int ep = tokEP[n * TOPK + k];
    rows[k] = off[ep >> 16] + (ep & 0xffff);
  }
  const int cc = tid * 8;
  float* po = out + (size_t)n * DIM + cc;
  float4 o0 = *reinterpret_cast<const float4*>(po);
  float4 o1 = *reinterpret_cast<const float4*>(po + 4);
  #pragma unroll
  for (int k = 0; k < TOPK; ++k) {
    const u16x8 v = *reinterpret_cast<const u16x8*>(P + (size_t)rows[k] * DIM + cc);
    o0.x += b2f(v[0]); o0.y += b2f(v[1]); o0.z += b2f(v[2]); o0.w += b2f(v[3]);
    o1.x += b2f(v[4]); o1.y += b2f(v[5]); o1.z += b2f(v[6]); o1.w += b2f(v[7]);
  }
  *reinterpret_cast<float4*>(po) = o0;
  *reinterpret_cast<float4*>(po + 4) = o1;
}

extern "C" void kernel_launch(void* const* d_in, const int* in_sizes, int n_in,
                              void* d_out, int out_size, void* d_ws, size_t ws_size,
                              hipStream_t stream) {
  const float* x   = (const float*)d_in[0];
  const float* rw  = (const float*)d_in[1];
  const float* rb  = (const float*)d_in[2];
  const float* wg  = (const float*)d_in[3];
  const float* wu  = (const float*)d_in[4];
  const float* wd  = (const float*)d_in[5];
  const float* swg = (const float*)d_in[6];
  const float* swu = (const float*)d_in[7];
  const float* swd = (const float*)d_in[8];
  float* out = (float*)d_out;
  char* ws = (char*)d_ws;

  int* cnt = (int*)ws;                                     // 256 B
  int* off = (int*)(ws + 256);                             // 256 B
  int* tokEP = (int*)(ws + 4096);                          // 32 KB
  int* listTok = (int*)(ws + 64 * 1024);                   // 512 KB
  float* listW = (float*)(ws + 576 * 1024);                // 512 KB
  unsigned short* xb   = (unsigned short*)(ws + (size_t) 2 * 1024 * 1024);  // 8 MB
  unsigned short* Hr   = (unsigned short*)(ws + (size_t)10 * 1024 * 1024);  // 8 MB
  unsigned short* Hs   = (unsigned short*)(ws + (size_t)18 * 1024 * 1024);  // 16 MB
  unsigned short* swuT = (unsigned short*)(ws + (size_t)34 * 1024 * 1024);  // 16 MB
  unsigned short* swgT = (unsigned short*)(ws + (size_t)50 * 1024 * 1024);  // 16 MB
  unsigned short* swdT = (unsigned short*)(ws + (size_t)66 * 1024 * 1024);  // 16 MB
  unsigned short* P    = (unsigned short*)(ws + (size_t)82 * 1024 * 1024);  // 32 MB -> 114 MB

  hipMemsetAsync(cnt, 0, NEXP * sizeof(int), stream);
  cvt_x_kernel<<<(N_TOK * DIM) / (256 * 8), 256, 0, stream>>>(x, xb);
  tr_shared_kernel<<<dim3(32, 32, 6), 256, 0, stream>>>(swu, swg, swd, swuT, swgT, swdT);
  router_kernel<<<N_TOK / 8, 256, 0, stream>>>(x, rw, rb, cnt, listTok, listW, tokEP);
  scan_kernel<<<1, 64, 0, stream>>>(cnt, off);

  up_routed<<<dim3(FDIM / 64, NEXP, 16), 256, 0, stream>>>(
      xb, wu, wg, cnt, off, listTok, listW, Hr);
  up_shared<<<dim3(HSH / 64, NSH, N_TOK / 128), 256, 0, stream>>>(
      xb, swuT, swgT, Hs);
  down_shared<<<dim3(DIM / 128, 1, N_TOK / 64), 256, 0, stream>>>(
      Hs, swdT, out);
  down_routed<<<dim3(DIM / 128, NEXP, 16), 256, 0, stream>>>(
      Hr, wd, cnt, off, P);
  combine_kernel<<<N_TOK, 256, 0, stream>>>(tokEP, off, P, out);
}

// Round 7
// 717.442 us; speedup vs baseline: 1.0079x; 1.0079x over previous
//
#include <hip/hip_runtime.h>
#include <hip/hip_bf16.h>

typedef __bf16 bf16x8 __attribute__((ext_vector_type(8)));
typedef float f32x4 __attribute__((ext_vector_type(4)));
typedef unsigned short u16x4 __attribute__((ext_vector_type(4)));
typedef unsigned short u16x8 __attribute__((ext_vector_type(8)));

#define DEVI __device__ __forceinline__

constexpr int N_TOK = 2048;   // B*T
constexpr int DIM   = 2048;   // D
constexpr int NEXP  = 64;     // E
constexpr int FDIM  = 512;    // F
constexpr int TOPK  = 4;      // K
constexpr int NSH   = 2;      // S
constexpr int HSH   = 2048;   // HS

#define WAIT_VM0 asm volatile("s_waitcnt vmcnt(0)" ::: "memory")
#define WAIT_VM3 asm volatile("s_waitcnt vmcnt(3)" ::: "memory")
#define WAIT_VM4 asm volatile("s_waitcnt vmcnt(4)" ::: "memory")
#define WAIT_VM6 asm volatile("s_waitcnt vmcnt(6)" ::: "memory")
#define WAIT_LG0 asm volatile("s_waitcnt lgkmcnt(0)" ::: "memory")
#define SBAR __builtin_amdgcn_s_barrier()

DEVI unsigned short f2b(float f) {
  union { float fv; unsigned u; } v; v.fv = f;
  unsigned r = v.u + 0x7fffu + ((v.u >> 16) & 1u);
  return (unsigned short)(r >> 16);
}
DEVI float b2f(unsigned short h) {
  union { unsigned u; float f; } v; v.u = ((unsigned)h) << 16;
  return v.f;
}
DEVI void gll16(const void* g, void* l) {
  __builtin_amdgcn_global_load_lds((const __attribute__((address_space(1))) unsigned*)g,
                                   (__attribute__((address_space(3))) unsigned*)l, 16, 0, 0);
}
DEVI unsigned cvtpk(float lo, float hi) {
  unsigned r;
  asm("v_cvt_pk_bf16_f32 %0, %1, %2" : "=v"(r) : "v"(lo), "v"(hi));
  return r;
}
// Build bf16x8 B-fragment from f32 LDS tile with row stride `str` floats.
DEVI bf16x8 fragB(const float* base, int str) {
  union { unsigned u[4]; bf16x8 v; } r;
  #pragma unroll
  for (int p = 0; p < 4; ++p) r.u[p] = cvtpk(base[(2 * p) * str], base[(2 * p + 1) * str]);
  return r.v;
}

// ---------------- x -> bf16 ----------------
__global__ void cvt_x_kernel(const float* __restrict__ x, unsigned short* __restrict__ xb) {
  const size_t i = ((size_t)blockIdx.x * 256 + threadIdx.x) * 8;
  const float4 a = *reinterpret_cast<const float4*>(x + i);
  const float4 b = *reinterpret_cast<const float4*>(x + i + 4);
  u16x8 o;
  o[0] = f2b(a.x); o[1] = f2b(a.y); o[2] = f2b(a.z); o[3] = f2b(a.w);
  o[4] = f2b(b.x); o[5] = f2b(b.y); o[6] = f2b(b.z); o[7] = f2b(b.w);
  *reinterpret_cast<u16x8*>(xb + i) = o;
}

// ---------------- shared weights: transpose + bf16 ----------------
__global__ __launch_bounds__(256)
void tr_shared_kernel(const float* __restrict__ swu, const float* __restrict__ swg,
                      const float* __restrict__ swd, unsigned short* __restrict__ swuT,
                      unsigned short* __restrict__ swgT, unsigned short* __restrict__ swdT) {
  __shared__ float Lf[64][68];
  const int tid = threadIdx.x;
  const int r0 = blockIdx.x * 64, c0 = blockIdx.y * 64;
  const int z = blockIdx.z, mat = z >> 1;
  const size_t soff = (size_t)(z & 1) * DIM * HSH;
  const float* in = (mat == 0 ? swu : mat == 1 ? swg : swd) + soff;
  unsigned short* ot = (mat == 0 ? swuT : mat == 1 ? swgT : swdT) + soff;
  #pragma unroll
  for (int j = 0; j < 4; ++j) {
    const int idx = j * 1024 + tid * 4;
    const int row = idx >> 6, col = idx & 63;
    const float4 v = *reinterpret_cast<const float4*>(in + (size_t)(r0 + row) * 2048 + c0 + col);
    *reinterpret_cast<float4*>(&Lf[row][col]) = v;
  }
  __syncthreads();
  #pragma unroll
  for (int j = 0; j < 4; ++j) {
    const int idx = j * 1024 + tid * 4;
    const int orow = idx >> 6, ocol = idx & 63;
    u16x4 o;
    o[0] = f2b(Lf[ocol][orow]);     o[1] = f2b(Lf[ocol + 1][orow]);
    o[2] = f2b(Lf[ocol + 2][orow]); o[3] = f2b(Lf[ocol + 3][orow]);
    *reinterpret_cast<u16x4*>(ot + (size_t)(c0 + orow) * 2048 + r0 + ocol) = o;
  }
}

// ---------------- Router ----------------
__global__ __launch_bounds__(256)
void router_kernel(const float* __restrict__ x, const float* __restrict__ rw,
                   const float* __restrict__ rb, int* __restrict__ cnt,
                   int* __restrict__ listTok, float* __restrict__ listW,
                   int* __restrict__ tokEP) {
  __shared__ float Lx[8][128];
  const int tid = threadIdx.x;
  const int lane = tid & 63;
  const int wave = tid >> 6;
  const int tokBase = blockIdx.x * 8;

  float acc0 = 0.f, acc1 = 0.f;
  for (int dc = 0; dc < DIM; dc += 128) {
    __syncthreads();
    {
      const int idx = tid * 4;
      const int row = idx >> 7, col = idx & 127;
      *reinterpret_cast<float4*>(&Lx[row][col]) =
          *reinterpret_cast<const float4*>(x + (size_t)(tokBase + row) * DIM + dc + col);
    }
    __syncthreads();
    #pragma unroll 16
    for (int dd = 0; dd < 128; ++dd) {
      const float r = rw[(size_t)(dc + dd) * NEXP + lane];
      acc0 = fmaf(Lx[wave * 2 + 0][dd], r, acc0);
      acc1 = fmaf(Lx[wave * 2 + 1][dd], r, acc1);
    }
  }

  const float bias = rb[lane];
  #pragma unroll
  for (int t = 0; t < 2; ++t) {
    const float v = (t == 0) ? acc0 : acc1;
    const int token = tokBase + wave * 2 + t;
    float m = v;
    #pragma unroll
    for (int o = 32; o > 0; o >>= 1) m = fmaxf(m, __shfl_xor(m, o));
    const float p = expf(v - m);
    float ss = p;
    #pragma unroll
    for (int o = 32; o > 0; o >>= 1) ss += __shfl_xor(ss, o);
    const float score = p / ss;
    float cur = v + bias;
    float wk[TOPK]; int ik[TOPK]; float wsum = 0.f;
    #pragma unroll
    for (int k = 0; k < TOPK; ++k) {
      float tm = cur;
      #pragma unroll
      for (int o = 32; o > 0; o >>= 1) tm = fmaxf(tm, __shfl_xor(tm, o));
      const unsigned long long msk = __ballot(cur == tm);
      const int sel = (int)__builtin_ctzll(msk);
      const float w = __shfl(score, sel);
      wk[k] = w; ik[k] = sel; wsum += w;
      if (lane == sel) cur = -3.4e38f;
    }
    if (lane < TOPK) {
      const int e = ik[lane];
      const float w = wk[lane] / wsum;
      const int slot = atomicAdd(&cnt[e], 1);
      listTok[(size_t)e * N_TOK + slot] = token;
      listW[(size_t)e * N_TOK + slot] = w;
      tokEP[token * TOPK + lane] = (e << 16) | slot;
    }
  }
}

__global__ void scan_kernel(const int* __restrict__ cnt, int* __restrict__ off) {
  if (threadIdx.x == 0) {
    int s = 0;
    for (int e = 0; e < NEXP; ++e) { off[e] = s; s += cnt[e]; }
  }
}

// ---------------- Routed up (fused U+G): BM=128, BN=64, BK=32, f32-B via gll16 ----------------
__global__ __launch_bounds__(256, 3)
void up_routed(const unsigned short* __restrict__ xb,
               const float* __restrict__ Wu, const float* __restrict__ Wg,
               const int* __restrict__ cnt, const int* __restrict__ off,
               const int* __restrict__ listTok, const float* __restrict__ listW,
               unsigned short* __restrict__ H) {
  constexpr int NT = DIM / 32;  // 64
  const int tid = threadIdx.x;
  const int f0 = blockIdx.x * 64;
  const int e  = blockIdx.y;
  const int m0 = blockIdx.z * 128;
  const int c = cnt[e];
  if (m0 >= c) return;
  const int rcnt = min(128, c - m0);
  const int rowbase = off[e] + m0;

  __shared__ __align__(16) unsigned short Al[2][4][128][8];   // 16 KB
  __shared__ __align__(16) float Bf[2][2][32][64];            // 32 KB
  __shared__ float wSs[128];

  if (tid < 128) wSs[tid] = (tid < rcnt) ? listW[(size_t)e * N_TOK + m0 + tid] : 0.f;
  WAIT_LG0;

  const int wid = tid >> 6, l = tid & 63;
  const int wm = wid >> 1, wn = wid & 1;
  const int lc = l & 15, hi = l >> 4;

  const int t0 = listTok[(size_t)e * N_TOK + m0 + min(l, rcnt - 1)];
  const int t1 = listTok[(size_t)e * N_TOK + m0 + min(64 + l, rcnt - 1)];
  const unsigned short* pa0 = xb + (size_t)t0 * DIM;
  const unsigned short* pa1 = xb + (size_t)t1 * DIM;
  const unsigned short* pas = (wid & 1) ? pa1 : pa0;
  const float* pbu = Wu + (size_t)e * DIM * FDIM + (size_t)(l >> 4) * FDIM + f0 + (l & 15) * 4;
  const float* pbg = Wg + (size_t)e * DIM * FDIM + (size_t)(l >> 4) * FDIM + f0 + (l & 15) * 4;

  auto stage = [&](int g, int b) {
    const int d0 = g * 32;
    gll16(pas + d0 + (wid >> 1) * 8,      &Al[b][wid >> 1][(wid & 1) * 64][0]);
    gll16(pas + d0 + (wid >> 1) * 8 + 16, &Al[b][(wid >> 1) + 2][(wid & 1) * 64][0]);
    gll16(pbu + (size_t)(d0 + 4 * wid) * FDIM,      &Bf[b][0][4 * wid][0]);
    gll16(pbu + (size_t)(d0 + 4 * wid + 16) * FDIM, &Bf[b][0][4 * wid + 16][0]);
    gll16(pbg + (size_t)(d0 + 4 * wid) * FDIM,      &Bf[b][1][4 * wid][0]);
    gll16(pbg + (size_t)(d0 + 4 * wid + 16) * FDIM, &Bf[b][1][4 * wid + 16][0]);
  };

  f32x4 aU[4][2], aG[4][2];
  #pragma unroll
  for (int i = 0; i < 4; ++i)
    #pragma unroll
    for (int j = 0; j < 2; ++j) { aU[i][j] = f32x4{0,0,0,0}; aG[i][j] = f32x4{0,0,0,0}; }

  stage(0, 0);
  for (int g = 0; g < NT; ++g) {
    const int b = g & 1;
    if (g + 1 < NT) { stage(g + 1, b ^ 1); WAIT_VM6; } else { WAIT_VM0; }
    SBAR;
    bf16x8 af[4];
    #pragma unroll
    for (int mi = 0; mi < 4; ++mi)
      af[mi] = *reinterpret_cast<const bf16x8*>(&Al[b][hi][wm * 64 + mi * 16 + lc][0]);
    #pragma unroll
    for (int ni = 0; ni < 2; ++ni) {
      const bf16x8 bu = fragB(&Bf[b][0][hi * 8][wn * 32 + ni * 16 + lc], 64);
      const bf16x8 bg = fragB(&Bf[b][1][hi * 8][wn * 32 + ni * 16 + lc], 64);
      #pragma unroll
      for (int mi = 0; mi < 4; ++mi) {
        aU[mi][ni] = __builtin_amdgcn_mfma_f32_16x16x32_bf16(af[mi], bu, aU[mi][ni], 0, 0, 0);
        aG[mi][ni] = __builtin_amdgcn_mfma_f32_16x16x32_bf16(af[mi], bg, aG[mi][ni], 0, 0, 0);
      }
    }
    SBAR;
  }

  #pragma unroll
  for (int mi = 0; mi < 4; ++mi)
    #pragma unroll
    for (int ni = 0; ni < 2; ++ni)
      #pragma unroll
      for (int r2 = 0; r2 < 4; ++r2) {
        const int row = wm * 64 + mi * 16 + hi * 4 + r2;
        if (row < rcnt) {
          const int col = f0 + wn * 32 + ni * 16 + lc;
          const float g = aG[mi][ni][r2], u = aU[mi][ni][r2];
          const float h = (g / (1.f + __expf(-g))) * u * wSs[row];
          H[(size_t)(rowbase + row) * FDIM + col] = f2b(h);
        }
      }
}

// ---------------- Routed down: BM=128, BN=128, BK=32, f32-B via gll16, P partials ----------------
__global__ __launch_bounds__(256, 3)
void down_routed(const unsigned short* __restrict__ Hr, const float* __restrict__ wd,
                 const int* __restrict__ cnt, const int* __restrict__ off,
                 unsigned short* __restrict__ P) {
  constexpr int NT = FDIM / 32;  // 16
  const int tid = threadIdx.x;
  const int x0 = blockIdx.x * 128;
  const int e  = blockIdx.y;
  const int m0 = blockIdx.z * 128;
  const int c = cnt[e];
  if (m0 >= c) return;
  const int rcnt = min(128, c - m0);
  const int rowbase = off[e] + m0;

  __shared__ __align__(16) unsigned short Al[2][4][128][8];   // 16 KB
  __shared__ __align__(16) float Bf[2][32][128];              // 32 KB

  const int wid = tid >> 6, l = tid & 63;
  const int wm = wid >> 1, wn = wid & 1;
  const int lc = l & 15, hi = l >> 4;

  const unsigned short* pa0 = Hr + (size_t)(rowbase + min(l, rcnt - 1)) * FDIM;
  const unsigned short* pa1 = Hr + (size_t)(rowbase + min(64 + l, rcnt - 1)) * FDIM;
  const unsigned short* pas = (wid & 1) ? pa1 : pa0;
  const float* pB = wd + (size_t)e * FDIM * DIM + (size_t)(l >> 5) * DIM + x0 + (l & 31) * 4;

  auto stage = [&](int g, int b) {
    const int d0 = g * 32;
    gll16(pas + d0 + (wid >> 1) * 8,      &Al[b][wid >> 1][(wid & 1) * 64][0]);
    gll16(pas + d0 + (wid >> 1) * 8 + 16, &Al[b][(wid >> 1) + 2][(wid & 1) * 64][0]);
    #pragma unroll
    for (int cc = 0; cc < 4; ++cc) {
      const int i = cc * 4 + wid;
      gll16(pB + (size_t)(d0 + 2 * i) * DIM, &Bf[b][2 * i][0]);
    }
  };

  f32x4 acc[4][4];
  #pragma unroll
  for (int i = 0; i < 4; ++i)
    #pragma unroll
    for (int j = 0; j < 4; ++j) acc[i][j] = f32x4{0,0,0,0};

  stage(0, 0);
  for (int g = 0; g < NT; ++g) {
    const int b = g & 1;
    if (g + 1 < NT) { stage(g + 1, b ^ 1); WAIT_VM6; } else { WAIT_VM0; }
    SBAR;
    bf16x8 af[4];
    #pragma unroll
    for (int mi = 0; mi < 4; ++mi)
      af[mi] = *reinterpret_cast<const bf16x8*>(&Al[b][hi][wm * 64 + mi * 16 + lc][0]);
    #pragma unroll
    for (int ni = 0; ni < 4; ++ni) {
      const bf16x8 bq = fragB(&Bf[b][hi * 8][wn * 64 + ni * 16 + lc], 128);
      #pragma unroll
      for (int mi = 0; mi < 4; ++mi)
        acc[mi][ni] = __builtin_amdgcn_mfma_f32_16x16x32_bf16(af[mi], bq, acc[mi][ni], 0, 0, 0);
    }
    SBAR;
  }

  #pragma unroll
  for (int mi = 0; mi < 4; ++mi)
    #pragma unroll
    for (int ni = 0; ni < 4; ++ni)
      #pragma unroll
      for (int r2 = 0; r2 < 4; ++r2) {
        const int row = wm * 64 + mi * 16 + hi * 4 + r2;
        if (row < rcnt) {
          const int col = x0 + wn * 64 + ni * 16 + lc;
          P[(size_t)(rowbase + row) * DIM + col] = f2b(acc[mi][ni][r2]);
        }
      }
}

// ---------------- Shared up (fused U+G): BM=128, BN=64, BK=32, all-bf16 gll16 ----------------
__global__ __launch_bounds__(256, 4)
void up_shared(const unsigned short* __restrict__ xb,
               const unsigned short* __restrict__ WuT, const unsigned short* __restrict__ WgT,
               unsigned short* __restrict__ H) {
  constexpr int NT = DIM / 32;  // 64
  const int tid = threadIdx.x;
  const int f0 = blockIdx.x * 64;
  const int s  = blockIdx.y;
  const int m0 = blockIdx.z * 128;

  __shared__ __align__(16) unsigned short Al[2][4][128][8];   // 16 KB
  __shared__ __align__(16) unsigned short Bu[2][4][64][8];    // 8 KB
  __shared__ __align__(16) unsigned short Bg[2][4][64][8];    // 8 KB

  const int wid = tid >> 6, l = tid & 63;
  const int wm = wid >> 1, wn = wid & 1;
  const int lc = l & 15, hi = l >> 4;

  const unsigned short* pa0 = xb + (size_t)(m0 + l) * DIM;
  const unsigned short* pa1 = xb + (size_t)(m0 + 64 + l) * DIM;
  const unsigned short* pas = (wid & 1) ? pa1 : pa0;
  const unsigned short* pbu = WuT + (size_t)s * HSH * DIM + (size_t)(f0 + l) * DIM;
  const unsigned short* pbg = WgT + (size_t)s * HSH * DIM + (size_t)(f0 + l) * DIM;

  auto stage = [&](int g, int b) {
    const int d0 = g * 32;
    gll16(pas + d0 + (wid >> 1) * 8,      &Al[b][wid >> 1][(wid & 1) * 64][0]);
    gll16(pas + d0 + (wid >> 1) * 8 + 16, &Al[b][(wid >> 1) + 2][(wid & 1) * 64][0]);
    gll16(pbu + d0 + wid * 8, &Bu[b][wid][0][0]);
    gll16(pbg + d0 + wid * 8, &Bg[b][wid][0][0]);
  };

  f32x4 aU[4][2], aG[4][2];
  #pragma unroll
  for (int i = 0; i < 4; ++i)
    #pragma unroll
    for (int j = 0; j < 2; ++j) { aU[i][j] = f32x4{0,0,0,0}; aG[i][j] = f32x4{0,0,0,0}; }

  stage(0, 0);
  for (int g = 0; g < NT; ++g) {
    const int b = g & 1;
    if (g + 1 < NT) { stage(g + 1, b ^ 1); WAIT_VM4; } else { WAIT_VM0; }
    SBAR;
    bf16x8 af[4], bu[2], bg[2];
    #pragma unroll
    for (int mi = 0; mi < 4; ++mi)
      af[mi] = *reinterpret_cast<const bf16x8*>(&Al[b][hi][wm * 64 + mi * 16 + lc][0]);
    #pragma unroll
    for (int ni = 0; ni < 2; ++ni) {
      bu[ni] = *reinterpret_cast<const bf16x8*>(&Bu[b][hi][wn * 32 + ni * 16 + lc][0]);
      bg[ni] = *reinterpret_cast<const bf16x8*>(&Bg[b][hi][wn * 32 + ni * 16 + lc][0]);
    }
    #pragma unroll
    for (int mi = 0; mi < 4; ++mi)
      #pragma unroll
      for (int ni = 0; ni < 2; ++ni) {
        aU[mi][ni] = __builtin_amdgcn_mfma_f32_16x16x32_bf16(af[mi], bu[ni], aU[mi][ni], 0, 0, 0);
        aG[mi][ni] = __builtin_amdgcn_mfma_f32_16x16x32_bf16(af[mi], bg[ni], aG[mi][ni], 0, 0, 0);
      }
    SBAR;
  }

  #pragma unroll
  for (int mi = 0; mi < 4; ++mi)
    #pragma unroll
    for (int ni = 0; ni < 2; ++ni)
      #pragma unroll
      for (int r2 = 0; r2 < 4; ++r2) {
        const int row = wm * 64 + mi * 16 + hi * 4 + r2;
        const int col = f0 + wn * 32 + ni * 16 + lc;
        const float g = aG[mi][ni][r2], u = aU[mi][ni][r2];
        H[((size_t)s * N_TOK + m0 + row) * HSH + col] = f2b((g / (1.f + __expf(-g))) * u);
      }
}

// ---------------- Shared down: BM=64, BN=128, BK=32, 2 segs, all-bf16 gll16 ----------------
__global__ __launch_bounds__(256, 4)
void down_shared(const unsigned short* __restrict__ Hs, const unsigned short* __restrict__ swdT,
                 float* __restrict__ out) {
  constexpr int NT = 2 * HSH / 32;  // 128
  const int tid = threadIdx.x;
  const int x0 = blockIdx.x * 128;
  const int m0 = blockIdx.z * 64;

  __shared__ __align__(16) unsigned short Al[2][4][64][8];    // 8 KB
  __shared__ __align__(16) unsigned short Bl[2][4][128][8];   // 16 KB

  const int wid = tid >> 6, l = tid & 63;
  const int wm = wid >> 1, wn = wid & 1;
  const int lc = l & 15, hi = l >> 4;

  const unsigned short* paA = Hs + (size_t)(m0 + l) * HSH;
  const unsigned short* pb0 = swdT + (size_t)(x0 + l) * HSH;
  const unsigned short* pb1 = swdT + (size_t)(x0 + 64 + l) * HSH;
  const unsigned short* pbs = (wid & 1) ? pb1 : pb0;

  auto stage = [&](int g, int b) {
    const int seg = g >> 6;
    const int dk = (g & 63) * 32;
    const size_t aoff = (size_t)seg * N_TOK * HSH;
    const size_t boff = (size_t)seg * HSH * DIM;
    gll16(paA + aoff + dk + wid * 8, &Al[b][wid][0][0]);
    gll16(pbs + boff + dk + (wid >> 1) * 8,      &Bl[b][wid >> 1][(wid & 1) * 64][0]);
    gll16(pbs + boff + dk + (wid >> 1) * 8 + 16, &Bl[b][(wid >> 1) + 2][(wid & 1) * 64][0]);
  };

  f32x4 acc[2][4];
  #pragma unroll
  for (int i = 0; i < 2; ++i)
    #pragma unroll
    for (int j = 0; j < 4; ++j) acc[i][j] = f32x4{0,0,0,0};

  stage(0, 0);
  for (int g = 0; g < NT; ++g) {
    const int b = g & 1;
    if (g + 1 < NT) { stage(g + 1, b ^ 1); WAIT_VM3; } else { WAIT_VM0; }
    SBAR;
    bf16x8 af[2], bq[4];
    #pragma unroll
    for (int mi = 0; mi < 2; ++mi)
      af[mi] = *reinterpret_cast<const bf16x8*>(&Al[b][hi][wm * 32 + mi * 16 + lc][0]);
    #pragma unroll
    for (int ni = 0; ni < 4; ++ni)
      bq[ni] = *reinterpret_cast<const bf16x8*>(&Bl[b][hi][wn * 64 + ni * 16 + lc][0]);
    #pragma unroll
    for (int mi = 0; mi < 2; ++mi)
      #pragma unroll
      for (int ni = 0; ni < 4; ++ni)
        acc[mi][ni] = __builtin_amdgcn_mfma_f32_16x16x32_bf16(af[mi], bq[ni], acc[mi][ni], 0, 0, 0);
    SBAR;
  }

  #pragma unroll
  for (int mi = 0; mi < 2; ++mi)
    #pragma unroll
    for (int ni = 0; ni < 4; ++ni)
      #pragma unroll
      for (int r2 = 0; r2 < 4; ++r2) {
        const int row = wm * 32 + mi * 16 + hi * 4 + r2;
        const int col = x0 + wn * 64 + ni * 16 + lc;
        out[(size_t)(m0 + row) * DIM + col] = acc[mi][ni][r2];
      }
}

// ---------------- Combine: out[n] += sum_k P[slot(n,k)] ----------------
__global__ __launch_bounds__(256)
void combine_kernel(const int* __restrict__ tokEP, const int* __restrict__ off,
                    const unsigned short* __restrict__ P, float* __restrict__ out) {
  const int n = blockIdx.x;
  const int tid = threadIdx.x;
  int rows[4];
  #pragma unroll
  for (int k = 0; k < TOPK; ++k) {
    const int ep = tokEP[n * TOPK + k];
    rows[k] = off[ep >> 16] + (ep & 0xffff);
  }
  const int cc = tid * 8;
  float* po = out + (size_t)n * DIM + cc;
  float4 o0 = *reinterpret_cast<const float4*>(po);
  float4 o1 = *reinterpret_cast<const float4*>(po + 4);
  #pragma unroll
  for (int k = 0; k < TOPK; ++k) {
    const u16x8 v = *reinterpret_cast<const u16x8*>(P + (size_t)rows[k] * DIM + cc);
    o0.x += b2f(v[0]); o0.y += b2f(v[1]); o0.z += b2f(v[2]); o0.w += b2f(v[3]);
    o1.x += b2f(v[4]); o1.y += b2f(v[5]); o1.z += b2f(v[6]); o1.w += b2f(v[7]);
  }
  *reinterpret_cast<float4*>(po) = o0;
  *reinterpret_cast<float4*>(po + 4) = o1;
}

extern "C" void kernel_launch(void* const* d_in, const int* in_sizes, int n_in,
                              void* d_out, int out_size, void* d_ws, size_t ws_size,
                              hipStream_t stream) {
  const float* x   = (const float*)d_in[0];
  const float* rw  = (const float*)d_in[1];
  const float* rb  = (const float*)d_in[2];
  const float* wg  = (const float*)d_in[3];
  const float* wu  = (const float*)d_in[4];
  const float* wd  = (const float*)d_in[5];
  const float* swg = (const float*)d_in[6];
  const float* swu = (const float*)d_in[7];
  const float* swd = (const float*)d_in[8];
  float* out = (float*)d_out;
  char* ws = (char*)d_ws;

  int* cnt = (int*)ws;                                     // 256 B
  int* off = (int*)(ws + 256);                             // 256 B
  int* tokEP = (int*)(ws + 4096);                          // 32 KB
  int* listTok = (int*)(ws + 64 * 1024);                   // 512 KB
  float* listW = (float*)(ws + 576 * 1024);                // 512 KB
  unsigned short* xb   = (unsigned short*)(ws + (size_t) 2 * 1024 * 1024);  // 8 MB
  unsigned short* Hr   = (unsigned short*)(ws + (size_t)10 * 1024 * 1024);  // 8 MB
  unsigned short* Hs   = (unsigned short*)(ws + (size_t)18 * 1024 * 1024);  // 16 MB
  unsigned short* swuT = (unsigned short*)(ws + (size_t)34 * 1024 * 1024);  // 16 MB
  unsigned short* swgT = (unsigned short*)(ws + (size_t)50 * 1024 * 1024);  // 16 MB
  unsigned short* swdT = (unsigned short*)(ws + (size_t)66 * 1024 * 1024);  // 16 MB
  unsigned short* P    = (unsigned short*)(ws + (size_t)82 * 1024 * 1024);  // 32 MB -> 114 MB

  hipMemsetAsync(cnt, 0, NEXP * sizeof(int), stream);
  cvt_x_kernel<<<(N_TOK * DIM) / (256 * 8), 256, 0, stream>>>(x, xb);
  tr_shared_kernel<<<dim3(32, 32, 6), 256, 0, stream>>>(swu, swg, swd, swuT, swgT, swdT);
  router_kernel<<<N_TOK / 8, 256, 0, stream>>>(x, rw, rb, cnt, listTok, listW, tokEP);
  scan_kernel<<<1, 64, 0, stream>>>(cnt, off);

  up_routed<<<dim3(FDIM / 64, NEXP, 16), 256, 0, stream>>>(
      xb, wu, wg, cnt, off, listTok, listW, Hr);
  up_shared<<<dim3(HSH / 64, NSH, N_TOK / 128), 256, 0, stream>>>(
      xb, swuT, swgT, Hs);
  down_shared<<<dim3(DIM / 128, 1, N_TOK / 64), 256, 0, stream>>>(
      Hs, swdT, out);
  down_routed<<<dim3(DIM / 128, NEXP, 16), 256, 0, stream>>>(
      Hr, wd, cnt, off, P);
  combine_kernel<<<N_TOK, 256, 0, stream>>>(tokEP, off, P, out);
}